// Round 4
// baseline (442.451 us; speedup 1.0000x reference)
//
#include <hip/hip_runtime.h>
#include <cstdint>
#include <cstddef>

// Problem constants (fixed by the reference)
#define NN 16384      // nodes
#define DIN 1024      // hid_size
#define DMID 1500     // hidden_size (logical)
#define DMIDP 1536    // padded to multiple of 128
#define NE 131072     // edges

typedef __bf16 bf16;
typedef __bf16 bf16x4 __attribute__((ext_vector_type(4)));
typedef __bf16 bf16x8 __attribute__((ext_vector_type(8)));
typedef float f32x4 __attribute__((ext_vector_type(4)));

#define GLOBAL_AS __attribute__((address_space(1)))
#define LDS_AS __attribute__((address_space(3)))

__device__ __forceinline__ void gload_lds16(const bf16* g, bf16* l) {
    // async 16B/lane global->LDS; LDS dest is wave-uniform base + lane*16
    __builtin_amdgcn_global_load_lds((GLOBAL_AS const unsigned int*)(g),
                                     (LDS_AS unsigned int*)(l), 16, 0, 0);
}

// ---------------- CSR build + normalization ----------------
__global__ void k_zero_cnt(int* cnt) {
    cnt[blockIdx.x * 256 + threadIdx.x] = 0;
}

__global__ void k_count(const int* __restrict__ dst, int* cnt) {
    int e = blockIdx.x * 256 + threadIdx.x;
    atomicAdd(&cnt[dst[e]], 1);
}

// single block, 1024 threads, 16 nodes each.
// rowptr = exclusive scan of PADDED counts (pad to multiple of 4); cursor = start; isd.
__global__ __launch_bounds__(1024) void k_scan(const int* __restrict__ cnt,
                                               int* __restrict__ rowptr,
                                               int* __restrict__ cursor,
                                               float* __restrict__ isd) {
    __shared__ int sums[1024];
    int t = threadIdx.x;
    int base = t * 16;
    int v[16], p[16];
    int s = 0;
#pragma unroll
    for (int k = 0; k < 16; ++k) {
        v[k] = cnt[base + k];
        p[k] = (v[k] + 3) & ~3;  // padded row length
        s += p[k];
    }
    sums[t] = s;
    __syncthreads();
    for (int off = 1; off < 1024; off <<= 1) {
        int y = (t >= off) ? sums[t - off] : 0;
        __syncthreads();
        sums[t] += y;
        __syncthreads();
    }
    int run = sums[t] - s;  // exclusive prefix
#pragma unroll
    for (int k = 0; k < 16; ++k) {
        rowptr[base + k] = run;
        cursor[base + k] = run;
        isd[base + k] = rsqrtf((float)(v[k] + 1));  // +1 self-loop
        run += p[k];
    }
    if (t == 1023) rowptr[NN] = run;
}

__global__ void k_fill(const int* __restrict__ src, const int* __restrict__ dst,
                       int* cursor, const float* __restrict__ isd,
                       int* __restrict__ csr_src, float* __restrict__ csr_w) {
    int e = blockIdx.x * 256 + threadIdx.x;
    int s = src[e], d = dst[e];
    int pos = atomicAdd(&cursor[d], 1);
    csr_src[pos] = s;
    csr_w[pos] = isd[s] * isd[d];
}

// fill pad slots: src = self (L1-hot row), w = 0 (contributes nothing)
__global__ void k_pad(const int* __restrict__ cnt, const int* __restrict__ rowptr,
                      int* __restrict__ csr_src, float* __restrict__ csr_w) {
    int i = blockIdx.x * 256 + threadIdx.x;
    int c = cnt[i];
    int p = (c + 3) & ~3;
    int base = rowptr[i];
    for (int q = c; q < p; ++q) {
        csr_src[base + q] = i;
        csr_w[base + q] = 0.0f;
    }
}

// ---------------- conversions ----------------
__global__ void k_cvt_x(const float4* __restrict__ x, bf16x4* __restrict__ xb) {
    int i = blockIdx.x * 256 + threadIdx.x;  // NN*DIN/4 total
    float4 v = x[i];
    bf16x4 o;
    o[0] = (bf16)v.x; o[1] = (bf16)v.y; o[2] = (bf16)v.z; o[3] = (bf16)v.w;
    xb[i] = o;
}

// W1 [1024][1500] f32 row-major -> W1b [1536][1024] bf16 (transposed, n-pad zero)
__global__ void k_cvt_w1(const float* __restrict__ W1, bf16* __restrict__ W1b) {
    int n = blockIdx.x;  // 0..1535
    for (int k = threadIdx.x; k < DIN; k += 256)
        W1b[n * DIN + k] = (n < DMID) ? (bf16)W1[(size_t)k * DMID + n] : (bf16)0.0f;
}

// W2 [1500][1024] f32 row-major -> W2b [1024][1536] bf16 (transposed, k-pad zero)
__global__ void k_cvt_w2(const float* __restrict__ W2, bf16* __restrict__ W2b) {
    int n = blockIdx.x;  // 0..1023
    for (int k = threadIdx.x; k < DMIDP; k += 256)
        W2b[n * DMIDP + k] = (k < DMID) ? (bf16)W2[(size_t)k * DIN + n] : (bf16)0.0f;
}

// ---------------- GEMM: C[M,N] = A[M,K] @ Bt[N,K]^T, bf16 in / bf16 out ----------------
// m97-style: 128x128 tile, BK=64, 4 waves, each wave 4x4 of 16x16x32 bf16 MFMA.
// grid.x = bm (fast dim; consecutive blocks share the 3 MB B panel in L2 — R3 showed
// bn-fast raises FETCH 61->141 MB and costs 4.4 us).
// RELU_BIAS: epilogue does relu(acc + bias[col]) (bias cols >= DMID read as 0).
template <bool RELU_BIAS>
__global__ __launch_bounds__(256) void gemm_bt(const bf16* __restrict__ A,
                                               const bf16* __restrict__ Bt,
                                               bf16* __restrict__ C,
                                               const float* __restrict__ bias,
                                               int M, int N, int K) {
    __shared__ __align__(16) bf16 sA[128 * 64];
    __shared__ __align__(16) bf16 sB[128 * 64];
    const int tid = threadIdx.x;
    const int wid = tid >> 6;
    const int lane = tid & 63;
    const int bm = blockIdx.x;
    const int bn = blockIdx.y;

    // staging: wave w covers rows 32w..32w+31 (4 loads of 8 rows), lane -> (row, col8)
    const int ldrow = (wid << 5) + (lane >> 3);
    const int ldcol = (lane & 7) << 3;
    const size_t aG = (size_t)(bm * 128 + ldrow) * K + ldcol;
    const size_t bG = (size_t)(bn * 128 + ldrow) * K + ldcol;
    bf16* sAw = sA + (wid << 5) * 64;  // wave-uniform LDS base
    bf16* sBw = sB + (wid << 5) * 64;

    const int wm = (wid & 1) << 6;   // wave's 64x64 quadrant
    const int wn = (wid >> 1) << 6;
    const int fr = lane & 15;
    const int fq = lane >> 4;

    f32x4 acc[4][4];
#pragma unroll
    for (int i = 0; i < 4; ++i)
#pragma unroll
        for (int j = 0; j < 4; ++j) acc[i][j] = {0.f, 0.f, 0.f, 0.f};

    for (int k0 = 0; k0 < K; k0 += 64) {
#pragma unroll
        for (int i = 0; i < 4; ++i)
            gload_lds16(A + aG + (size_t)(8 * i) * K + k0, sAw + i * 512);
#pragma unroll
        for (int i = 0; i < 4; ++i)
            gload_lds16(Bt + bG + (size_t)(8 * i) * K + k0, sBw + i * 512);
        __syncthreads();
#pragma unroll
        for (int s = 0; s < 2; ++s) {
            bf16x8 af[4], bf_[4];
#pragma unroll
            for (int mt = 0; mt < 4; ++mt)
                af[mt] = *(const bf16x8*)&sA[(wm + mt * 16 + fr) * 64 + s * 32 + fq * 8];
#pragma unroll
            for (int nt = 0; nt < 4; ++nt)
                bf_[nt] = *(const bf16x8*)&sB[(wn + nt * 16 + fr) * 64 + s * 32 + fq * 8];
#pragma unroll
            for (int mt = 0; mt < 4; ++mt)
#pragma unroll
                for (int nt = 0; nt < 4; ++nt)
                    acc[mt][nt] = __builtin_amdgcn_mfma_f32_16x16x32_bf16(
                        af[mt], bf_[nt], acc[mt][nt], 0, 0, 0);
        }
        __syncthreads();
    }

    // C/D layout (verified m89/m91): col = lane&15, row = (lane>>4)*4 + reg
#pragma unroll
    for (int nt = 0; nt < 4; ++nt) {
        int col = bn * 128 + wn + nt * 16 + fr;
        float b = 0.0f;
        if (RELU_BIAS) b = (col < DMID) ? bias[col] : 0.0f;
#pragma unroll
        for (int mt = 0; mt < 4; ++mt) {
            int row0 = bm * 128 + wm + mt * 16 + fq * 4;
#pragma unroll
            for (int r = 0; r < 4; ++r) {
                float v = acc[mt][nt][r];
                if (RELU_BIAS) v = fmaxf(v + b, 0.0f);
                C[(size_t)(row0 + r) * N + col] = (bf16)v;
            }
        }
    }
}

// ---------------- aggregation (CSR gather, barrier-free) ----------------
// Edge lists padded to multiples of 4; metadata loads are block-uniform (scalar);
// 4 independent 16 B row-gathers in flight per thread per iteration.

// XA[i] = isd_i^2 * X[i] + sum_j w_ij * X[j], 1024-wide bf16 in/out
__global__ __launch_bounds__(128) void k_aggX(const bf16* __restrict__ X,
                                              const int* __restrict__ rowptr,
                                              const int* __restrict__ csr_src,
                                              const float* __restrict__ csr_w,
                                              const float* __restrict__ isd,
                                              bf16* __restrict__ XA) {
    int i = blockIdx.x;
    int t = threadIdx.x;      // 128 threads * 8 cols = 1024
    int c0 = t * 8;
    int beg = rowptr[i], end = rowptr[i + 1];  // uniform; (end-beg) % 4 == 0
    float wi = isd[i];
    float w0 = wi * wi;
    float a[8];
    bf16x8 h = *(const bf16x8*)&X[(size_t)i * DIN + c0];
#pragma unroll
    for (int k = 0; k < 8; ++k) a[k] = w0 * (float)h[k];
    for (int e = beg; e < end; e += 4) {
        int j0 = csr_src[e + 0], j1 = csr_src[e + 1];
        int j2 = csr_src[e + 2], j3 = csr_src[e + 3];
        float wa = csr_w[e + 0], wb = csr_w[e + 1];
        float wc = csr_w[e + 2], wd = csr_w[e + 3];
        bf16x8 h0 = *(const bf16x8*)&X[(size_t)j0 * DIN + c0];
        bf16x8 h1 = *(const bf16x8*)&X[(size_t)j1 * DIN + c0];
        bf16x8 h2 = *(const bf16x8*)&X[(size_t)j2 * DIN + c0];
        bf16x8 h3 = *(const bf16x8*)&X[(size_t)j3 * DIN + c0];
#pragma unroll
        for (int k = 0; k < 8; ++k) a[k] += wa * (float)h0[k];
#pragma unroll
        for (int k = 0; k < 8; ++k) a[k] += wb * (float)h1[k];
#pragma unroll
        for (int k = 0; k < 8; ++k) a[k] += wc * (float)h2[k];
#pragma unroll
        for (int k = 0; k < 8; ++k) a[k] += wd * (float)h3[k];
    }
    bf16x8 o;
#pragma unroll
    for (int k = 0; k < 8; ++k) o[k] = (bf16)a[k];
    *(bf16x8*)&XA[(size_t)i * DIN + c0] = o;
}

// layer 2: out[i] = isd_i^2 * H[i] + sum_j w_ij * H[j] + b2, f32 out
__global__ __launch_bounds__(128) void k_agg2(const bf16* __restrict__ H,
                                              const int* __restrict__ rowptr,
                                              const int* __restrict__ csr_src,
                                              const float* __restrict__ csr_w,
                                              const float* __restrict__ isd,
                                              const float* __restrict__ b2,
                                              float* __restrict__ out) {
    int i = blockIdx.x;
    int t = threadIdx.x;      // 128 threads * 8 cols = 1024
    int c0 = t * 8;
    int beg = rowptr[i], end = rowptr[i + 1];
    float wi = isd[i];
    float w0 = wi * wi;
    float a[8];
    bf16x8 h = *(const bf16x8*)&H[(size_t)i * DIN + c0];
#pragma unroll
    for (int k = 0; k < 8; ++k) a[k] = w0 * (float)h[k];
    for (int e = beg; e < end; e += 4) {
        int j0 = csr_src[e + 0], j1 = csr_src[e + 1];
        int j2 = csr_src[e + 2], j3 = csr_src[e + 3];
        float wa = csr_w[e + 0], wb = csr_w[e + 1];
        float wc = csr_w[e + 2], wd = csr_w[e + 3];
        bf16x8 h0 = *(const bf16x8*)&H[(size_t)j0 * DIN + c0];
        bf16x8 h1 = *(const bf16x8*)&H[(size_t)j1 * DIN + c0];
        bf16x8 h2 = *(const bf16x8*)&H[(size_t)j2 * DIN + c0];
        bf16x8 h3 = *(const bf16x8*)&H[(size_t)j3 * DIN + c0];
#pragma unroll
        for (int k = 0; k < 8; ++k) a[k] += wa * (float)h0[k];
#pragma unroll
        for (int k = 0; k < 8; ++k) a[k] += wb * (float)h1[k];
#pragma unroll
        for (int k = 0; k < 8; ++k) a[k] += wc * (float)h2[k];
#pragma unroll
        for (int k = 0; k < 8; ++k) a[k] += wd * (float)h3[k];
    }
    float4 o0, o1;
    o0.x = a[0] + b2[c0 + 0]; o0.y = a[1] + b2[c0 + 1];
    o0.z = a[2] + b2[c0 + 2]; o0.w = a[3] + b2[c0 + 3];
    o1.x = a[4] + b2[c0 + 4]; o1.y = a[5] + b2[c0 + 5];
    o1.z = a[6] + b2[c0 + 6]; o1.w = a[7] + b2[c0 + 7];
    *(float4*)&out[(size_t)i * DIN + c0] = o0;
    *(float4*)&out[(size_t)i * DIN + c0 + 4] = o1;
}

extern "C" void kernel_launch(void* const* d_in, const int* in_sizes, int n_in,
                              void* d_out, int out_size, void* d_ws, size_t ws_size,
                              hipStream_t stream) {
    const float* x = (const float*)d_in[0];
    const int* ei = (const int*)d_in[1];
    const float* W1 = (const float*)d_in[2];
    const float* b1 = (const float*)d_in[3];
    const float* W2 = (const float*)d_in[4];
    const float* b2 = (const float*)d_in[5];
    float* out = (float*)d_out;
    const int* src = ei;
    const int* dst = ei + NE;

    // workspace layout (bytes), total ~120.3 MB
    char* ws = (char*)d_ws;
    int* cnt      = (int*)(ws + 0);          //  64 KB
    int* cursor   = (int*)(ws + 65536);      //  64 KB
    float* isd    = (float*)(ws + 131072);   //  64 KB
    int* rowptr   = (int*)(ws + 196608);     // 128 KB (NN+1 ints)
    int* csr_src  = (int*)(ws + 327680);     //   1 MB (padded <= 180224 entries)
    float* csr_w  = (float*)(ws + 1376256);  //   1 MB
    bf16* Xb      = (bf16*)(ws + 2424832);   // 33.55 MB (16384x1024)
    bf16* XA      = (bf16*)(ws + 35979264);  // 33.55 MB — reused as H2b
    bf16* W1b     = (bf16*)(ws + 69533696);  //  3.15 MB (1536x1024, transposed)
    bf16* W2b     = (bf16*)(ws + 72679424);  //  3.15 MB (1024x1536, transposed)
    bf16* Y1b     = (bf16*)(ws + 75825152);  // 50.33 MB (16384x1536)
    bf16* H2b     = XA;                      // XA dead after GEMM1

    // CSR + normalization
    k_zero_cnt<<<NN / 256, 256, 0, stream>>>(cnt);
    k_count<<<NE / 256, 256, 0, stream>>>(dst, cnt);
    k_scan<<<1, 1024, 0, stream>>>(cnt, rowptr, cursor, isd);
    k_fill<<<NE / 256, 256, 0, stream>>>(src, dst, cursor, isd, csr_src, csr_w);
    k_pad<<<NN / 256, 256, 0, stream>>>(cnt, rowptr, csr_src, csr_w);

    // bf16 conversions
    k_cvt_x<<<NN * DIN / 4 / 256, 256, 0, stream>>>((const float4*)x, (bf16x4*)Xb);
    k_cvt_w1<<<DMIDP, 256, 0, stream>>>(W1, W1b);
    k_cvt_w2<<<DIN, 256, 0, stream>>>(W2, W2b);

    // layer 1: XA = A_hat @ X ; Y1 = relu(XA @ W1 + b1)   [agg commutes with linear]
    k_aggX<<<NN, 128, 0, stream>>>(Xb, rowptr, csr_src, csr_w, isd, XA);
    dim3 g1(NN / 128, DMIDP / 128);
    gemm_bt<true><<<g1, 256, 0, stream>>>(XA, W1b, Y1b, b1, NN, DMIDP, DIN);

    // layer 2: H2 = Y1 @ W2 ; out = A_hat @ H2 + b2
    dim3 g2(NN / 128, DIN / 128);
    gemm_bt<false><<<g2, 256, 0, stream>>>(Y1b, W2b, H2b, nullptr, NN, DIN, DMIDP);
    k_agg2<<<NN, 128, 0, stream>>>(H2b, rowptr, csr_src, csr_w, isd, b2, out);
}

// Round 5
// 433.855 us; speedup vs baseline: 1.0198x; 1.0198x over previous
//
#include <hip/hip_runtime.h>
#include <cstdint>
#include <cstddef>

// Problem constants (fixed by the reference)
#define NN 16384      // nodes
#define DIN 1024      // hid_size
#define DMID 1500     // hidden_size (logical)
#define DMIDP 1536    // padded to multiple of 128
#define NE 131072     // edges

typedef __bf16 bf16;
typedef __bf16 bf16x4 __attribute__((ext_vector_type(4)));
typedef __bf16 bf16x8 __attribute__((ext_vector_type(8)));
typedef float f32x4 __attribute__((ext_vector_type(4)));

#define GLOBAL_AS __attribute__((address_space(1)))
#define LDS_AS __attribute__((address_space(3)))

__device__ __forceinline__ void gload_lds16(const bf16* g, bf16* l) {
    // async 16B/lane global->LDS; LDS dest is wave-uniform base + lane*16
    __builtin_amdgcn_global_load_lds((GLOBAL_AS const unsigned int*)(g),
                                     (LDS_AS unsigned int*)(l), 16, 0, 0);
}

// ---------------- CSR build + normalization ----------------
__global__ void k_zero_cnt(int* cnt) {
    cnt[blockIdx.x * 256 + threadIdx.x] = 0;
}

__global__ void k_count(const int* __restrict__ dst, int* cnt) {
    int e = blockIdx.x * 256 + threadIdx.x;
    atomicAdd(&cnt[dst[e]], 1);
}

// single block, 1024 threads, 16 nodes each.
// rowptr = exclusive scan of PADDED counts (pad to multiple of 8); cursor = start; isd.
__global__ __launch_bounds__(1024) void k_scan(const int* __restrict__ cnt,
                                               int* __restrict__ rowptr,
                                               int* __restrict__ cursor,
                                               float* __restrict__ isd) {
    __shared__ int sums[1024];
    int t = threadIdx.x;
    int base = t * 16;
    int v[16], p[16];
    int s = 0;
#pragma unroll
    for (int k = 0; k < 16; ++k) {
        v[k] = cnt[base + k];
        p[k] = (v[k] + 7) & ~7;  // padded row length (multiple of 8)
        s += p[k];
    }
    sums[t] = s;
    __syncthreads();
    for (int off = 1; off < 1024; off <<= 1) {
        int y = (t >= off) ? sums[t - off] : 0;
        __syncthreads();
        sums[t] += y;
        __syncthreads();
    }
    int run = sums[t] - s;  // exclusive prefix
#pragma unroll
    for (int k = 0; k < 16; ++k) {
        rowptr[base + k] = run;
        cursor[base + k] = run;
        isd[base + k] = rsqrtf((float)(v[k] + 1));  // +1 self-loop
        run += p[k];
    }
    if (t == 1023) rowptr[NN] = run;
}

__global__ void k_fill(const int* __restrict__ src, const int* __restrict__ dst,
                       int* cursor, const float* __restrict__ isd,
                       int* __restrict__ csr_src, float* __restrict__ csr_w) {
    int e = blockIdx.x * 256 + threadIdx.x;
    int s = src[e], d = dst[e];
    int pos = atomicAdd(&cursor[d], 1);
    csr_src[pos] = s;
    csr_w[pos] = isd[s] * isd[d];
}

// fill pad slots: src = self (L1-hot row), w = 0 (contributes nothing)
__global__ void k_pad(const int* __restrict__ cnt, const int* __restrict__ rowptr,
                      int* __restrict__ csr_src, float* __restrict__ csr_w) {
    int i = blockIdx.x * 256 + threadIdx.x;
    int c = cnt[i];
    int p = (c + 7) & ~7;
    int base = rowptr[i];
    for (int q = c; q < p; ++q) {
        csr_src[base + q] = i;
        csr_w[base + q] = 0.0f;
    }
}

// ---------------- conversions ----------------
__global__ void k_cvt_x(const float4* __restrict__ x, bf16x4* __restrict__ xb) {
    int i = blockIdx.x * 256 + threadIdx.x;  // NN*DIN/4 total
    float4 v = x[i];
    bf16x4 o;
    o[0] = (bf16)v.x; o[1] = (bf16)v.y; o[2] = (bf16)v.z; o[3] = (bf16)v.w;
    xb[i] = o;
}

// W1 [1024][1500] f32 row-major -> W1b [1536][1024] bf16 (transposed, n-pad zero)
__global__ void k_cvt_w1(const float* __restrict__ W1, bf16* __restrict__ W1b) {
    int n = blockIdx.x;  // 0..1535
    for (int k = threadIdx.x; k < DIN; k += 256)
        W1b[n * DIN + k] = (n < DMID) ? (bf16)W1[(size_t)k * DMID + n] : (bf16)0.0f;
}

// W2 [1500][1024] f32 row-major -> W2b [1024][1536] bf16 (transposed, k-pad zero)
__global__ void k_cvt_w2(const float* __restrict__ W2, bf16* __restrict__ W2b) {
    int n = blockIdx.x;  // 0..1023
    for (int k = threadIdx.x; k < DMIDP; k += 256)
        W2b[n * DMIDP + k] = (k < DMID) ? (bf16)W2[(size_t)k * DIN + n] : (bf16)0.0f;
}

// ---------------- GEMM: C[M,N] = A[M,K] @ Bt[N,K]^T, bf16 in / bf16 out ----------------
// m97-style: 128x128 tile, BK=64, 4 waves, each wave 4x4 of 16x16x32 bf16 MFMA.
// grid.x = bm (fast; R3 showed bn-fast costs FETCH 61->141 MB, +4.4 us).
// Epilogue is EXACTLY the R2 order (mt outer) — R4's nt-outer order cost +17 us
// stall and +16 MB WRITE_SIZE (partial-line writebacks).
template <bool RELU_BIAS>
__global__ __launch_bounds__(256) void gemm_bt(const bf16* __restrict__ A,
                                               const bf16* __restrict__ Bt,
                                               bf16* __restrict__ C,
                                               const float* __restrict__ bias,
                                               int M, int N, int K) {
    __shared__ __align__(16) bf16 sA[128 * 64];
    __shared__ __align__(16) bf16 sB[128 * 64];
    const int tid = threadIdx.x;
    const int wid = tid >> 6;
    const int lane = tid & 63;
    const int bm = blockIdx.x;
    const int bn = blockIdx.y;

    // staging: wave w covers rows 32w..32w+31 (4 loads of 8 rows), lane -> (row, col8)
    const int ldrow = (wid << 5) + (lane >> 3);
    const int ldcol = (lane & 7) << 3;
    const size_t aG = (size_t)(bm * 128 + ldrow) * K + ldcol;
    const size_t bG = (size_t)(bn * 128 + ldrow) * K + ldcol;
    bf16* sAw = sA + (wid << 5) * 64;  // wave-uniform LDS base
    bf16* sBw = sB + (wid << 5) * 64;

    const int wm = (wid & 1) << 6;   // wave's 64x64 quadrant
    const int wn = (wid >> 1) << 6;
    const int fr = lane & 15;
    const int fq = lane >> 4;

    f32x4 acc[4][4];
#pragma unroll
    for (int i = 0; i < 4; ++i)
#pragma unroll
        for (int j = 0; j < 4; ++j) acc[i][j] = {0.f, 0.f, 0.f, 0.f};

    for (int k0 = 0; k0 < K; k0 += 64) {
#pragma unroll
        for (int i = 0; i < 4; ++i)
            gload_lds16(A + aG + (size_t)(8 * i) * K + k0, sAw + i * 512);
#pragma unroll
        for (int i = 0; i < 4; ++i)
            gload_lds16(Bt + bG + (size_t)(8 * i) * K + k0, sBw + i * 512);
        __syncthreads();
#pragma unroll
        for (int s = 0; s < 2; ++s) {
            bf16x8 af[4], bf_[4];
#pragma unroll
            for (int mt = 0; mt < 4; ++mt)
                af[mt] = *(const bf16x8*)&sA[(wm + mt * 16 + fr) * 64 + s * 32 + fq * 8];
#pragma unroll
            for (int nt = 0; nt < 4; ++nt)
                bf_[nt] = *(const bf16x8*)&sB[(wn + nt * 16 + fr) * 64 + s * 32 + fq * 8];
#pragma unroll
            for (int mt = 0; mt < 4; ++mt)
#pragma unroll
                for (int nt = 0; nt < 4; ++nt)
                    acc[mt][nt] = __builtin_amdgcn_mfma_f32_16x16x32_bf16(
                        af[mt], bf_[nt], acc[mt][nt], 0, 0, 0);
        }
        __syncthreads();
    }

    // bias per (nt) column, hoisted out of the store loops
    float bv[4];
    if (RELU_BIAS) {
#pragma unroll
        for (int nt = 0; nt < 4; ++nt) {
            int col = bn * 128 + wn + nt * 16 + fr;
            bv[nt] = (col < DMID) ? bias[col] : 0.0f;
        }
    }

    // C/D layout (verified m89/m91): col = lane&15, row = (lane>>4)*4 + reg
    // R2-proven store order: mt outer, nt, r inner.
#pragma unroll
    for (int mt = 0; mt < 4; ++mt) {
        int row0 = bm * 128 + wm + mt * 16 + fq * 4;
#pragma unroll
        for (int nt = 0; nt < 4; ++nt) {
            int col = bn * 128 + wn + nt * 16 + fr;
#pragma unroll
            for (int r = 0; r < 4; ++r) {
                float v = acc[mt][nt][r];
                if (RELU_BIAS) v = fmaxf(v + bv[nt], 0.0f);
                C[(size_t)(row0 + r) * N + col] = (bf16)v;
            }
        }
    }
}

// ---------------- aggregation (CSR gather, barrier-free) ----------------
// Edge lists padded to multiples of 8; metadata loads are block-uniform (scalar);
// 8 independent 16 B row-gathers in flight per thread per iteration.

// XA[i] = isd_i^2 * X[i] + sum_j w_ij * X[j], 1024-wide bf16 in/out
__global__ __launch_bounds__(128) void k_aggX(const bf16* __restrict__ X,
                                              const int* __restrict__ rowptr,
                                              const int* __restrict__ csr_src,
                                              const float* __restrict__ csr_w,
                                              const float* __restrict__ isd,
                                              bf16* __restrict__ XA) {
    int i = blockIdx.x;
    int t = threadIdx.x;      // 128 threads * 8 cols = 1024
    int c0 = t * 8;
    int beg = rowptr[i], end = rowptr[i + 1];  // uniform; (end-beg) % 8 == 0
    float wi = isd[i];
    float w0 = wi * wi;
    float a[8];
    bf16x8 h = *(const bf16x8*)&X[(size_t)i * DIN + c0];
#pragma unroll
    for (int k = 0; k < 8; ++k) a[k] = w0 * (float)h[k];
    for (int e = beg; e < end; e += 8) {
        int j[8];
        float w[8];
        bf16x8 hv[8];
#pragma unroll
        for (int q = 0; q < 8; ++q) { j[q] = csr_src[e + q]; w[q] = csr_w[e + q]; }
#pragma unroll
        for (int q = 0; q < 8; ++q)
            hv[q] = *(const bf16x8*)&X[(size_t)j[q] * DIN + c0];
#pragma unroll
        for (int q = 0; q < 8; ++q)
#pragma unroll
            for (int k = 0; k < 8; ++k) a[k] += w[q] * (float)hv[q][k];
    }
    bf16x8 o;
#pragma unroll
    for (int k = 0; k < 8; ++k) o[k] = (bf16)a[k];
    *(bf16x8*)&XA[(size_t)i * DIN + c0] = o;
}

// layer 2: out[i] = isd_i^2 * H[i] + sum_j w_ij * H[j] + b2, f32 out
__global__ __launch_bounds__(128) void k_agg2(const bf16* __restrict__ H,
                                              const int* __restrict__ rowptr,
                                              const int* __restrict__ csr_src,
                                              const float* __restrict__ csr_w,
                                              const float* __restrict__ isd,
                                              const float* __restrict__ b2,
                                              float* __restrict__ out) {
    int i = blockIdx.x;
    int t = threadIdx.x;      // 128 threads * 8 cols = 1024
    int c0 = t * 8;
    int beg = rowptr[i], end = rowptr[i + 1];
    float wi = isd[i];
    float w0 = wi * wi;
    float a[8];
    bf16x8 h = *(const bf16x8*)&H[(size_t)i * DIN + c0];
#pragma unroll
    for (int k = 0; k < 8; ++k) a[k] = w0 * (float)h[k];
    for (int e = beg; e < end; e += 8) {
        int j[8];
        float w[8];
        bf16x8 hv[8];
#pragma unroll
        for (int q = 0; q < 8; ++q) { j[q] = csr_src[e + q]; w[q] = csr_w[e + q]; }
#pragma unroll
        for (int q = 0; q < 8; ++q)
            hv[q] = *(const bf16x8*)&H[(size_t)j[q] * DIN + c0];
#pragma unroll
        for (int q = 0; q < 8; ++q)
#pragma unroll
            for (int k = 0; k < 8; ++k) a[k] += w[q] * (float)hv[q][k];
    }
    float4 o0, o1;
    o0.x = a[0] + b2[c0 + 0]; o0.y = a[1] + b2[c0 + 1];
    o0.z = a[2] + b2[c0 + 2]; o0.w = a[3] + b2[c0 + 3];
    o1.x = a[4] + b2[c0 + 4]; o1.y = a[5] + b2[c0 + 5];
    o1.z = a[6] + b2[c0 + 6]; o1.w = a[7] + b2[c0 + 7];
    *(float4*)&out[(size_t)i * DIN + c0] = o0;
    *(float4*)&out[(size_t)i * DIN + c0 + 4] = o1;
}

extern "C" void kernel_launch(void* const* d_in, const int* in_sizes, int n_in,
                              void* d_out, int out_size, void* d_ws, size_t ws_size,
                              hipStream_t stream) {
    const float* x = (const float*)d_in[0];
    const int* ei = (const int*)d_in[1];
    const float* W1 = (const float*)d_in[2];
    const float* b1 = (const float*)d_in[3];
    const float* W2 = (const float*)d_in[4];
    const float* b2 = (const float*)d_in[5];
    float* out = (float*)d_out;
    const int* src = ei;
    const int* dst = ei + NE;

    // workspace layout (bytes), total ~122 MB
    char* ws = (char*)d_ws;
    int* cnt      = (int*)(ws + 0);          //  64 KB
    int* cursor   = (int*)(ws + 65536);      //  64 KB
    float* isd    = (float*)(ws + 131072);   //  64 KB
    int* rowptr   = (int*)(ws + 196608);     // 128 KB (NN+1 ints)
    int* csr_src  = (int*)(ws + 327680);     //   2 MB (padded <= 245760 entries)
    float* csr_w  = (float*)(ws + 2424832);  //   2 MB
    bf16* Xb      = (bf16*)(ws + 4521984);   // 33.55 MB (16384x1024)
    bf16* XA      = (bf16*)(ws + 38076416);  // 33.55 MB — reused as H2b
    bf16* W1b     = (bf16*)(ws + 71630848);  //  3.15 MB (1536x1024, transposed)
    bf16* W2b     = (bf16*)(ws + 74776576);  //  3.15 MB (1024x1536, transposed)
    bf16* Y1b     = (bf16*)(ws + 77922304);  // 50.33 MB (16384x1536)
    bf16* H2b     = XA;                      // XA dead after GEMM1

    // CSR + normalization
    k_zero_cnt<<<NN / 256, 256, 0, stream>>>(cnt);
    k_count<<<NE / 256, 256, 0, stream>>>(dst, cnt);
    k_scan<<<1, 1024, 0, stream>>>(cnt, rowptr, cursor, isd);
    k_fill<<<NE / 256, 256, 0, stream>>>(src, dst, cursor, isd, csr_src, csr_w);
    k_pad<<<NN / 256, 256, 0, stream>>>(cnt, rowptr, csr_src, csr_w);

    // bf16 conversions
    k_cvt_x<<<NN * DIN / 4 / 256, 256, 0, stream>>>((const float4*)x, (bf16x4*)Xb);
    k_cvt_w1<<<DMIDP, 256, 0, stream>>>(W1, W1b);
    k_cvt_w2<<<DIN, 256, 0, stream>>>(W2, W2b);

    // layer 1: XA = A_hat @ X ; Y1 = relu(XA @ W1 + b1)   [agg commutes with linear]
    k_aggX<<<NN, 128, 0, stream>>>(Xb, rowptr, csr_src, csr_w, isd, XA);
    dim3 g1(NN / 128, DMIDP / 128);
    gemm_bt<true><<<g1, 256, 0, stream>>>(XA, W1b, Y1b, b1, NN, DMIDP, DIN);

    // layer 2: H2 = Y1 @ W2 ; out = A_hat @ H2 + b2
    dim3 g2(NN / 128, DIN / 128);
    gemm_bt<false><<<g2, 256, 0, stream>>>(Y1b, W2b, H2b, nullptr, NN, DIN, DMIDP);
    k_agg2<<<NN, 128, 0, stream>>>(H2b, rowptr, csr_src, csr_w, isd, b2, out);
}